// Round 3
// baseline (144.513 us; speedup 1.0000x reference)
//
#include <hip/hip_runtime.h>
#include <hip/hip_fp16.h>
#include <cstdint>

typedef _Float16 half8_t __attribute__((ext_vector_type(8)));
typedef float f32x4 __attribute__((ext_vector_type(4)));

#define D_ 1024
#define B_ 4
#define N_ 2048
#define M_ (B_*N_)   // 8192 rows
#define NC_ 3072     // fused q|k|v output cols

// ---------------- workspace layout (bytes, all 256-aligned) ----------------
#define OFF_WCAT  0u            // 3072*1024*2  = 6291456
#define OFF_BCAT  6291456u      // 3072*4       = 12288
#define OFF_XB    6303744u      // 8192*1024*2  = 16777216
#define OFF_Q     23080960u
#define OFF_K     39858176u
#define OFF_V     56635392u
#define OFF_ZP    73412608u     // 8192*32*4    = 1048576
#define OFF_DEXP  74461184u     // 8192*4
#define OFF_SV    74493952u     // 4*16*1024*4  = 262144
#define OFF_INVD  74756096u     // 8192*4
#define OFF_CD    74788864u     // 8192*4

// ---------------- async global->LDS, 16B per lane ----------------
__device__ __forceinline__ void gload_lds16(const void* g, void* l) {
  __builtin_amdgcn_global_load_lds(
      (const __attribute__((address_space(1))) unsigned int*)(uintptr_t)g,
      (__attribute__((address_space(3))) unsigned int*)(uintptr_t)l, 16, 0, 0);
}

// ============================================================================
// 128^2 m97-structure core (round-1 proven; used by k_stats)
// ============================================================================
__device__ __forceinline__ void stage128x64(const __half* rowbase, char* lds, int tid) {
#pragma unroll
  for (int inst = 0; inst < 4; ++inst) {
    int L  = inst * 4096 + tid * 16;
    int r  = L >> 7;
    int cb = L & 127;
    int cbs = cb ^ ((r & 7) << 4);
    gload_lds16((const char*)rowbase + (size_t)r * (D_ * 2) + cbs, lds + L);
  }
}

__device__ __forceinline__ half8_t ldsfrag(const char* lds, int row, int cbyte) {
  int b = (row << 7) + (cbyte ^ ((row & 7) << 4));
  return *reinterpret_cast<const half8_t*>(lds + b);
}

__device__ __forceinline__ void gemm128_core(const __half* Arow0, const __half* Brow0,
                                             char* As, char* Bs, f32x4 acc[4][4]) {
  const int tid  = threadIdx.x;
  const int lane = tid & 63;
  const int wave = tid >> 6;
  const int wm = wave >> 1, wn = wave & 1;
  for (int kt = 0; kt < 16; ++kt) {
    if (kt) __syncthreads();
    stage128x64(Arow0 + kt * 64, As, tid);
    stage128x64(Brow0 + kt * 64, Bs, tid);
    asm volatile("s_waitcnt vmcnt(0)" ::: "memory");
    __syncthreads();
#pragma unroll
    for (int kk = 0; kk < 2; ++kk) {
      const int cbyte = kk * 64 + (lane >> 4) * 16;
      half8_t a[4], b[4];
#pragma unroll
      for (int mf = 0; mf < 4; ++mf) a[mf] = ldsfrag(As, wm * 64 + mf * 16 + (lane & 15), cbyte);
#pragma unroll
      for (int nf = 0; nf < 4; ++nf) b[nf] = ldsfrag(Bs, wn * 64 + nf * 16 + (lane & 15), cbyte);
#pragma unroll
      for (int mf = 0; mf < 4; ++mf)
#pragma unroll
        for (int nf = 0; nf < 4; ++nf)
          acc[mf][nf] = __builtin_amdgcn_mfma_f32_16x16x32_f16(a[mf], b[nf], acc[mf][nf], 0, 0, 0);
    }
  }
}

// ============================================================================
// 256x192 8-phase counted-vmcnt core (k_qkv). BK=64, 16 K-tiles, 8 iterations
// of 2 tiles. buf0 = even tiles, buf1 = odd. Stage t+2 in ph3, t+3 in ph7;
// vmcnt(7) at ph3/ph7 drains exactly the next-needed tile (4-phase distance).
// LDS subtiled [r>>4][kb>>6][16][32] with st_16x32 swizzle; global source is
// pre-swizzled so global_load_lds dest stays linear.
// ============================================================================

#define G01(QM)                                                              \
  _Pragma("unroll") for (int ks = 0; ks < 2; ++ks)                           \
  _Pragma("unroll") for (int mf = 0; mf < 4; ++mf)                           \
  _Pragma("unroll") for (int nf = 0; nf < 2; ++nf)                           \
    acc[(QM)*4+mf][nf] = __builtin_amdgcn_mfma_f32_16x16x32_f16(             \
        a[mf][ks], b[nf][ks], acc[(QM)*4+mf][nf], 0, 0, 0);

#define G2(QM)                                                               \
  _Pragma("unroll") for (int ks = 0; ks < 2; ++ks)                           \
  _Pragma("unroll") for (int mf = 0; mf < 4; ++mf)                           \
    acc[(QM)*4+mf][2] = __builtin_amdgcn_mfma_f32_16x16x32_f16(              \
        a[mf][ks], b[2][ks], acc[(QM)*4+mf][2], 0, 0, 0);

#define QKV_HALF(APTR, BPTR, AgN, BgN, PRE)                                  \
  {                                                                          \
    const half8_t* ap = (const half8_t*)((APTR) + wm * 16384 + wlane);       \
    const half8_t* bp = (const half8_t*)((BPTR) + wn * 6144  + wlane);       \
    /* ph0: a(qm0) + b(nf0,1); MFMA qm0 x nf01 */                            \
    _Pragma("unroll") for (int mf = 0; mf < 4; ++mf)                         \
    _Pragma("unroll") for (int ks = 0; ks < 2; ++ks)                         \
      a[mf][ks] = ap[(mf * 2 + ks) * 64];                                    \
    _Pragma("unroll") for (int nf = 0; nf < 2; ++nf)                         \
    _Pragma("unroll") for (int ks = 0; ks < 2; ++ks)                         \
      b[nf][ks] = bp[(nf * 2 + ks) * 64];                                    \
    __builtin_amdgcn_s_barrier();                                            \
    asm volatile("s_waitcnt lgkmcnt(0)" ::: "memory");                       \
    __builtin_amdgcn_s_setprio(1); G01(0) __builtin_amdgcn_s_setprio(0);     \
    __builtin_amdgcn_s_barrier();                                            \
    /* ph1: b(nf2); MFMA qm0 x nf2 */                                        \
    _Pragma("unroll") for (int ks = 0; ks < 2; ++ks)                         \
      b[2][ks] = bp[(4 + ks) * 64];                                          \
    __builtin_amdgcn_s_barrier();                                            \
    asm volatile("s_waitcnt lgkmcnt(0)" ::: "memory");                       \
    __builtin_amdgcn_s_setprio(1); G2(0) __builtin_amdgcn_s_setprio(0);      \
    __builtin_amdgcn_s_barrier();                                            \
    /* ph2: a(qm1); MFMA qm1 x nf01 */                                       \
    _Pragma("unroll") for (int mf = 0; mf < 4; ++mf)                         \
    _Pragma("unroll") for (int ks = 0; ks < 2; ++ks)                         \
      a[mf][ks] = ap[((4 + mf) * 2 + ks) * 64];                              \
    __builtin_amdgcn_s_barrier();                                            \
    asm volatile("s_waitcnt lgkmcnt(0)" ::: "memory");                       \
    __builtin_amdgcn_s_setprio(1); G01(1) __builtin_amdgcn_s_setprio(0);     \
    __builtin_amdgcn_s_barrier();                                            \
    /* ph3: stage next-next tile into this buffer; MFMA qm1 x nf2 */         \
    if (PRE) {                                                               \
      _Pragma("unroll") for (int i2 = 0; i2 < 4; ++i2)                       \
        gload_lds16((AgN) + soffA[i2], (APTR) + i2 * 8192 + tid * 16);       \
      _Pragma("unroll") for (int i2 = 0; i2 < 3; ++i2)                       \
        gload_lds16((BgN) + soffB[i2], (BPTR) + i2 * 8192 + tid * 16);       \
    }                                                                        \
    __builtin_amdgcn_s_barrier();                                            \
    asm volatile("s_waitcnt lgkmcnt(0)" ::: "memory");                       \
    __builtin_amdgcn_s_setprio(1); G2(1) __builtin_amdgcn_s_setprio(0);      \
    if (PRE) asm volatile("s_waitcnt vmcnt(7)" ::: "memory");                \
    else     asm volatile("s_waitcnt vmcnt(0)" ::: "memory");                \
    __builtin_amdgcn_s_barrier();                                            \
  }

// ---------------- K1: fp32->fp16 convert + zero partials ----------------
__global__ __launch_bounds__(256) void k_prep(
    const float* __restrict__ x, const float* __restrict__ wq, const float* __restrict__ wk,
    const float* __restrict__ wv, const float* __restrict__ bq, const float* __restrict__ bk,
    const float* __restrict__ bv, __half* __restrict__ xb, __half* __restrict__ wcat,
    float* __restrict__ bcat, float* __restrict__ Zpart) {
  const int NX4 = (M_ * D_) / 4;
  const int NW4 = (D_ * D_) / 4;
  const int TOT = NX4 + 3 * NW4;
  int tid0 = blockIdx.x * 256 + threadIdx.x;
  int stride = gridDim.x * 256;
  for (int i = tid0; i < TOT; i += stride) {
    float4 f; __half* dst;
    if (i < NX4) {
      f = ((const float4*)x)[i];
      dst = xb + 4 * (size_t)i;
    } else {
      int j = i - NX4; int w = j / NW4; int o = j - w * NW4;
      const float* src = (w == 0) ? wq : (w == 1) ? wk : wv;
      f = ((const float4*)src)[o];
      dst = wcat + (size_t)w * (D_ * D_) + 4 * (size_t)o;
    }
    __half h0 = __float2half(f.x), h1 = __float2half(f.y),
           h2 = __float2half(f.z), h3 = __float2half(f.w);
    ushort4 u = { __half_as_ushort(h0), __half_as_ushort(h1),
                  __half_as_ushort(h2), __half_as_ushort(h3) };
    *((ushort4*)dst) = u;
  }
  if (tid0 < NC_)
    bcat[tid0] = (tid0 < 1024) ? bq[tid0] : (tid0 < 2048) ? bk[tid0 - 1024] : bv[tid0 - 2048];
  for (int i = tid0; i < M_ * 32; i += stride) Zpart[i] = 0.f;
}

// ---------------- K2: fused QKV GEMM (256x192, 8-phase counted) -----------
__global__ __launch_bounds__(512, 2) void k_qkv192(
    const __half* __restrict__ xb, const __half* __restrict__ wcat,
    const float* __restrict__ bcat,
    __half* __restrict__ q, __half* __restrict__ kx, __half* __restrict__ v) {
  __shared__ __align__(16) char smem[114688];   // buf0: A@0 B@32768; buf1: A@57344 B@90112
  const int tid  = threadIdx.x;
  const int lane = tid & 63;
  const int wave = tid >> 6;
  const int wm = wave >> 2, wn = wave & 3;

  int bid = blockIdx.x;
  int tile = (bid & 7) * 64 + (bid >> 3);       // XCD-chunked, 512 = 8*64
  int bm = tile >> 4, bn = tile & 15;           // 32 x 16

  // preload bias BEFORE the K-loop so no VMEM op pollutes vmcnt counting
  float bias[3];
#pragma unroll
  for (int nf = 0; nf < 3; ++nf)
    bias[nf] = bcat[bn * 192 + wn * 48 + nf * 16 + (lane & 15)];
  asm volatile("" :: "v"(bias[0]), "v"(bias[1]), "v"(bias[2]));

  // pre-swizzled global source offsets (LDS dest linear)
  int soffA[4], soffB[3];
#pragma unroll
  for (int i = 0; i < 4; ++i) {
    int L = i * 8192 + tid * 16;
    int s = L >> 10, w = L & 1023;
    w ^= ((w >> 9) & 1) << 5;
    soffA[i] = ((s >> 1) * 16 + (w >> 6)) * 2048 + ((s & 1) * 64 + (w & 63));
  }
#pragma unroll
  for (int i = 0; i < 3; ++i) {
    int L = i * 8192 + tid * 16;
    int s = L >> 10, w = L & 1023;
    w ^= ((w >> 9) & 1) << 5;
    soffB[i] = ((s >> 1) * 16 + (w >> 6)) * 2048 + ((s & 1) * 64 + (w & 63));
  }
  const int wlane = (((lane & 15) * 64 + (lane >> 4) * 16)) ^ (((lane >> 3) & 1) << 5);

  const char* Ag = (const char*)(xb + (size_t)bm * 256 * D_);
  const char* Bg = (const char*)(wcat + (size_t)bn * 192 * D_);
  char* A0 = smem;           char* B0 = smem + 32768;
  char* A1 = smem + 57344;   char* B1 = smem + 90112;

  f32x4 acc[8][3];
#pragma unroll
  for (int i = 0; i < 8; ++i)
#pragma unroll
    for (int j = 0; j < 3; ++j) acc[i][j] = f32x4{0.f, 0.f, 0.f, 0.f};

  // prologue: tile0 -> buf0, tile1 -> buf1; drain tile0 only (7 left in flight)
#pragma unroll
  for (int i = 0; i < 4; ++i) gload_lds16(Ag + soffA[i], A0 + i * 8192 + tid * 16);
#pragma unroll
  for (int i = 0; i < 3; ++i) gload_lds16(Bg + soffB[i], B0 + i * 8192 + tid * 16);
#pragma unroll
  for (int i = 0; i < 4; ++i) gload_lds16(Ag + 128 + soffA[i], A1 + i * 8192 + tid * 16);
#pragma unroll
  for (int i = 0; i < 3; ++i) gload_lds16(Bg + 128 + soffB[i], B1 + i * 8192 + tid * 16);
  asm volatile("s_waitcnt vmcnt(7)" ::: "memory");
  __builtin_amdgcn_s_barrier();

  half8_t a[4][2], b[3][2];
  for (int it = 0; it < 8; ++it) {
    const bool pre = (it < 7);
    const char* Ag2 = Ag + (2 * it + 2) * 128;
    const char* Bg2 = Bg + (2 * it + 2) * 128;
    const char* Ag3 = Ag + (2 * it + 3) * 128;
    const char* Bg3 = Bg + (2 * it + 3) * 128;
    QKV_HALF(A0, B0, Ag2, Bg2, pre)   // tile 2it   (phases 0-3)
    QKV_HALF(A1, B1, Ag3, Bg3, pre)   // tile 2it+1 (phases 4-7)
  }

  // epilogue: per-16-col fragment never straddles a q/k/v boundary
#pragma unroll
  for (int nf = 0; nf < 3; ++nf) {
    int gcol = bn * 192 + wn * 48 + nf * 16 + (lane & 15);
    int sel = gcol >> 10, col = gcol & 1023;
    __half* outp = (sel == 0) ? q : (sel == 1) ? kx : v;
#pragma unroll
    for (int mf = 0; mf < 8; ++mf) {
#pragma unroll
      for (int rr = 0; rr < 4; ++rr) {
        int m = bm * 256 + wm * 128 + mf * 16 + (lane >> 4) * 4 + rr;
        outp[(size_t)m * D_ + col] = __float2half(acc[mf][nf][rr] + bias[nf]);
      }
    }
  }
}

// ---------------- K3: upper-triangle QK^T row stats (128^2 core) ----------
__global__ __launch_bounds__(256) void k_stats(
    const __half* __restrict__ q, const __half* __restrict__ kx,
    float* __restrict__ Zpart, float* __restrict__ dexp) {
  __shared__ __align__(16) char smem[32768];
  int bid = blockIdx.x;
  int b = bid / 136;
  int r = bid % 136;
  int ti = 0;
  while (r >= 16 - ti) { r -= 16 - ti; ++ti; }
  int tj = ti + r;

  f32x4 acc[4][4];
#pragma unroll
  for (int i = 0; i < 4; ++i)
#pragma unroll
    for (int j = 0; j < 4; ++j) acc[i][j] = f32x4{0.f, 0.f, 0.f, 0.f};
  const size_t base = (size_t)b * N_ * D_;
  gemm128_core(q + base + (size_t)ti * 128 * D_, kx + base + (size_t)tj * 128 * D_,
               smem, smem + 16384, acc);

  const int lane = threadIdx.x & 63;
  const int wave = threadIdx.x >> 6;
  const int wm = wave >> 1, wn = wave & 1;
  const bool offd = (tj > ti);
  const float scale = 0.03125f;            // 1/sqrt(1024)
  int zrow0 = b * N_ + ti * 128;
#pragma unroll
  for (int mf = 0; mf < 4; ++mf) {
#pragma unroll
    for (int rg = 0; rg < 4; ++rg) {
      int il = wm * 64 + mf * 16 + (lane >> 4) * 4 + rg;
      float ssum = 0.f;
#pragma unroll
      for (int nf = 0; nf < 4; ++nf) {
        int jl = wn * 64 + nf * 16 + (lane & 15);
        float e = __expf(acc[mf][nf][rg] * scale);
        bool keep = offd || (jl >= il);
        if (!offd && jl == il) dexp[zrow0 + il] = e;
        ssum += keep ? e : 0.f;
      }
      ssum += __shfl_xor(ssum, 1);
      ssum += __shfl_xor(ssum, 2);
      ssum += __shfl_xor(ssum, 4);
      ssum += __shfl_xor(ssum, 8);
      if ((lane & 15) == 0)
        Zpart[(size_t)(zrow0 + il) * 32 + tj * 2 + wn] = ssum;
    }
  }
}

// ---------------- K4a: v chunk sums + per-row 1/D, dexp/D ----------------
__global__ __launch_bounds__(256) void k_mid(
    const __half* __restrict__ v, const float* __restrict__ Zpart,
    const float* __restrict__ dexp, float* __restrict__ Sv,
    float* __restrict__ invD, float* __restrict__ cdiag) {
  int tid = blockIdx.x * 256 + threadIdx.x;     // 65536 threads
  int b = tid >> 14, c = (tid >> 10) & 15, d = tid & 1023;
  const __half* vp = v + ((size_t)(b * N_ + c * 128)) * D_ + d;
  float s = 0.f;
#pragma unroll 8
  for (int r2 = 0; r2 < 128; ++r2) s += __half2float(vp[(size_t)r2 * D_]);
  Sv[tid] = s;
  if (tid < M_) {
    float z = 0.f;
#pragma unroll
    for (int t = 0; t < 32; ++t) z += Zpart[(size_t)tid * 32 + t];
    float Dd = (float)(tid & (N_ - 1)) + z;     // i + sum_{j>=i} exp(s_ij)
    float iv = 1.f / Dd;
    invD[tid] = iv;
    cdiag[tid] = dexp[tid] * iv;
  }
}

// ---------------- K4b: prefix-scan blend -> output ----------------
__global__ __launch_bounds__(256) void k_out(
    const __half* __restrict__ v, const float* __restrict__ Sv,
    const float* __restrict__ invD, const float* __restrict__ cdiag,
    float* __restrict__ out) {
  int tid = blockIdx.x * 256 + threadIdx.x;
  int b = tid >> 14, c = (tid >> 10) & 15, d = tid & 1023;
  float run = 0.f;
  for (int cc = 0; cc < c; ++cc) run += Sv[((b << 4) + cc) * 1024 + d];
  const __half* vp = v + ((size_t)(b * N_ + c * 128)) * D_ + d;
  float* op = out + ((size_t)(b * N_ + c * 128)) * D_ + d;
  int zi0 = b * N_ + c * 128;
#pragma unroll 4
  for (int r2 = 0; r2 < 128; ++r2) {
    float vi = __half2float(vp[(size_t)r2 * D_]);
    op[(size_t)r2 * D_] = run * invD[zi0 + r2] + cdiag[zi0 + r2] * vi;
    run += vi;
  }
}

extern "C" void kernel_launch(void* const* d_in, const int* in_sizes, int n_in,
                              void* d_out, int out_size, void* d_ws, size_t ws_size,
                              hipStream_t stream) {
  const float* x  = (const float*)d_in[0];
  const float* wq = (const float*)d_in[1];
  const float* bq = (const float*)d_in[2];
  const float* wk = (const float*)d_in[3];
  const float* bk = (const float*)d_in[4];
  const float* wv = (const float*)d_in[5];
  const float* bv = (const float*)d_in[6];
  float* out = (float*)d_out;
  char* ws = (char*)d_ws;

  __half* wcat = (__half*)(ws + OFF_WCAT);
  float*  bcat = (float*)(ws + OFF_BCAT);
  __half* xb   = (__half*)(ws + OFF_XB);
  __half* q    = (__half*)(ws + OFF_Q);
  __half* k    = (__half*)(ws + OFF_K);
  __half* v    = (__half*)(ws + OFF_V);
  float* Zpart = (float*)(ws + OFF_ZP);
  float* dexp  = (float*)(ws + OFF_DEXP);
  float* Sv    = (float*)(ws + OFF_SV);
  float* invD  = (float*)(ws + OFF_INVD);
  float* cdiag = (float*)(ws + OFF_CD);

  k_prep<<<dim3(2048), dim3(256), 0, stream>>>(x, wq, wk, wv, bq, bk, bv, xb, wcat, bcat, Zpart);
  k_qkv192<<<dim3(512), dim3(512), 0, stream>>>(xb, wcat, bcat, q, k, v);
  k_stats<<<dim3(4 * 136), dim3(256), 0, stream>>>(q, k, Zpart, dexp);
  k_mid<<<dim3(256), dim3(256), 0, stream>>>(v, Zpart, dexp, Sv, invD, cdiag);
  k_out<<<dim3(256), dim3(256), 0, stream>>>(v, Sv, invD, cdiag, out);
}

// Round 4
// 137.392 us; speedup vs baseline: 1.0518x; 1.0518x over previous
//
#include <hip/hip_runtime.h>
#include <hip/hip_fp16.h>
#include <cstdint>

typedef _Float16 half8_t __attribute__((ext_vector_type(8)));
typedef float f32x4 __attribute__((ext_vector_type(4)));

#define D_ 1024
#define B_ 4
#define N_ 2048
#define M_ (B_*N_)   // 8192 rows
#define NC_ 3072     // fused q|k|v output cols

// ---------------- workspace layout (bytes, all 256-aligned) ----------------
#define OFF_WCAT  0u            // 3072*1024*2  = 6291456
#define OFF_BCAT  6291456u      // 3072*4       = 12288
#define OFF_XB    6303744u      // 8192*1024*2  = 16777216
#define OFF_Q     23080960u
#define OFF_K     39858176u
#define OFF_V     56635392u
#define OFF_ZP    73412608u     // 8192*32*4    = 1048576
#define OFF_DEXP  74461184u     // 8192*4
#define OFF_SV    74493952u     // 4*16*1024*4  = 262144
#define OFF_INVD  74756096u     // 8192*4
#define OFF_CD    74788864u     // 8192*4

// ---------------- async global->LDS, 16B per lane ----------------
__device__ __forceinline__ void gload_lds16(const void* g, void* l) {
  __builtin_amdgcn_global_load_lds(
      (const __attribute__((address_space(1))) unsigned int*)(uintptr_t)g,
      (__attribute__((address_space(3))) unsigned int*)(uintptr_t)l, 16, 0, 0);
}

// ============================================================================
// 128^2 m97-structure core (round-1 proven, 874 TF-class) — used by k_qkv
// ============================================================================
__device__ __forceinline__ void stage128x64(const __half* rowbase, char* lds, int tid) {
#pragma unroll
  for (int inst = 0; inst < 4; ++inst) {
    int L  = inst * 4096 + tid * 16;
    int r  = L >> 7;
    int cb = L & 127;
    int cbs = cb ^ ((r & 7) << 4);
    gload_lds16((const char*)rowbase + (size_t)r * (D_ * 2) + cbs, lds + L);
  }
}

__device__ __forceinline__ half8_t ldsfrag(const char* lds, int row, int cbyte) {
  int b = (row << 7) + (cbyte ^ ((row & 7) << 4));
  return *reinterpret_cast<const half8_t*>(lds + b);
}

__device__ __forceinline__ void gemm128_core(const __half* Arow0, const __half* Brow0,
                                             char* As, char* Bs, f32x4 acc[4][4]) {
  const int tid  = threadIdx.x;
  const int lane = tid & 63;
  const int wave = tid >> 6;
  const int wm = wave >> 1, wn = wave & 1;
  for (int kt = 0; kt < 16; ++kt) {
    if (kt) __syncthreads();
    stage128x64(Arow0 + kt * 64, As, tid);
    stage128x64(Brow0 + kt * 64, Bs, tid);
    asm volatile("s_waitcnt vmcnt(0)" ::: "memory");
    __syncthreads();
#pragma unroll
    for (int kk = 0; kk < 2; ++kk) {
      const int cbyte = kk * 64 + (lane >> 4) * 16;
      half8_t a[4], b[4];
#pragma unroll
      for (int mf = 0; mf < 4; ++mf) a[mf] = ldsfrag(As, wm * 64 + mf * 16 + (lane & 15), cbyte);
#pragma unroll
      for (int nf = 0; nf < 4; ++nf) b[nf] = ldsfrag(Bs, wn * 64 + nf * 16 + (lane & 15), cbyte);
#pragma unroll
      for (int mf = 0; mf < 4; ++mf)
#pragma unroll
        for (int nf = 0; nf < 4; ++nf)
          acc[mf][nf] = __builtin_amdgcn_mfma_f32_16x16x32_f16(a[mf], b[nf], acc[mf][nf], 0, 0, 0);
    }
  }
}

// ============================================================================
// 256^2 8-phase core (round-2 proven for k_stats256)
// ============================================================================
__device__ __forceinline__ void calc_soff(int tid, int soff[4]) {
#pragma unroll
  for (int i = 0; i < 4; ++i) {
    int L = i * 8192 + tid * 16;          // linear LDS byte this lane writes
    int s = L >> 10;
    int w = L & 1023;
    w ^= ((w >> 9) & 1) << 5;             // unswizzle -> logical (r,kb)
    int r  = (s >> 1) * 16 + (w >> 6);
    int kb = (s & 1) * 64 + (w & 63);
    soff[i] = r * 2048 + kb;              // global byte offset (row stride 2048)
  }
}

#define MFMA_QUAD(QM, QN)                                                     \
  _Pragma("unroll")                                                           \
  for (int ks = 0; ks < 2; ++ks)                                              \
    _Pragma("unroll")                                                         \
    for (int mf = 0; mf < 4; ++mf)                                            \
      _Pragma("unroll")                                                       \
      for (int nf = 0; nf < 2; ++nf)                                          \
        acc[(QM)*4 + mf][(QN)*2 + nf] = __builtin_amdgcn_mfma_f32_16x16x32_f16( \
            a[mf][ks], b[(QN)][nf][ks], acc[(QM)*4 + mf][(QN)*2 + nf], 0, 0, 0);

__device__ __forceinline__ void gemm256_8ph(const char* Ag, const char* Bg,
                                            char* smem, f32x4 acc[8][4]) {
  const int tid  = threadIdx.x;
  const int lane = tid & 63;
  const int wave = tid >> 6;
  const int wm = wave >> 2, wn = wave & 3;

  int soff[4];
  calc_soff(tid, soff);
  const int wlane = (((lane & 15) * 64 + (lane >> 4) * 16)) ^ (((lane >> 3) & 1) << 5);

  // prologue: stage K-tile 0 into buf0
#pragma unroll
  for (int i = 0; i < 4; ++i) gload_lds16(Ag + soff[i], smem + i * 8192 + tid * 16);
#pragma unroll
  for (int i = 0; i < 4; ++i) gload_lds16(Bg + soff[i], smem + 32768 + i * 8192 + tid * 16);
  asm volatile("s_waitcnt vmcnt(0)" ::: "memory");
  __builtin_amdgcn_s_barrier();

  for (int t = 0; t < 16; ++t) {
    char* A0  = smem + ((t & 1) << 16);
    char* B0  = A0 + 32768;
    char* A1  = smem + (((t + 1) & 1) << 16);
    char* B1s = A1 + 32768;
    const half8_t* ap = (const half8_t*)(A0 + wm * 16384 + wlane);
    const half8_t* bp = (const half8_t*)(B0 + wn * 8192 + wlane);
    const char* Agn = Ag + (t + 1) * 128;
    const char* Bgn = Bg + (t + 1) * 128;
    const bool pre = (t < 15);

    half8_t a[4][2];
    half8_t b[2][2][2];

    // -------- phase 0: read A(qm=0) + B(qn=0); prefetch next A --------
#pragma unroll
    for (int mf = 0; mf < 4; ++mf)
#pragma unroll
      for (int ks = 0; ks < 2; ++ks)
        a[mf][ks] = ap[(mf * 2 + ks) * 64];
#pragma unroll
    for (int nf = 0; nf < 2; ++nf)
#pragma unroll
      for (int ks = 0; ks < 2; ++ks)
        b[0][nf][ks] = bp[(nf * 2 + ks) * 64];
    if (pre) {
#pragma unroll
      for (int i = 0; i < 4; ++i) gload_lds16(Agn + soff[i], A1 + i * 8192 + tid * 16);
    }
    __builtin_amdgcn_s_barrier();
    asm volatile("s_waitcnt lgkmcnt(0)" ::: "memory");
    __builtin_amdgcn_s_setprio(1);
    MFMA_QUAD(0, 0)
    __builtin_amdgcn_s_setprio(0);
    __builtin_amdgcn_s_barrier();

    // -------- phase 1: read B(qn=1); prefetch next B --------
#pragma unroll
    for (int nf = 0; nf < 2; ++nf)
#pragma unroll
      for (int ks = 0; ks < 2; ++ks)
        b[1][nf][ks] = bp[((2 + nf) * 2 + ks) * 64];
    if (pre) {
#pragma unroll
      for (int i = 0; i < 4; ++i) gload_lds16(Bgn + soff[i], B1s + i * 8192 + tid * 16);
    }
    __builtin_amdgcn_s_barrier();
    asm volatile("s_waitcnt lgkmcnt(0)" ::: "memory");
    __builtin_amdgcn_s_setprio(1);
    MFMA_QUAD(0, 1)
    __builtin_amdgcn_s_setprio(0);
    __builtin_amdgcn_s_barrier();

    // -------- phase 2: read A(qm=1) --------
#pragma unroll
    for (int mf = 0; mf < 4; ++mf)
#pragma unroll
      for (int ks = 0; ks < 2; ++ks)
        a[mf][ks] = ap[((4 + mf) * 2 + ks) * 64];
    __builtin_amdgcn_s_barrier();
    asm volatile("s_waitcnt lgkmcnt(0)" ::: "memory");
    __builtin_amdgcn_s_setprio(1);
    MFMA_QUAD(1, 0)
    __builtin_amdgcn_s_setprio(0);
    __builtin_amdgcn_s_barrier();

    // -------- phase 3: no new reads --------
    __builtin_amdgcn_s_setprio(1);
    MFMA_QUAD(1, 1)
    __builtin_amdgcn_s_setprio(0);
    if (pre) asm volatile("s_waitcnt vmcnt(0)" ::: "memory");
    __builtin_amdgcn_s_barrier();
  }
}

// ---------------- K1: fp32->fp16 convert + zero partials ----------------
__global__ __launch_bounds__(256) void k_prep(
    const float* __restrict__ x, const float* __restrict__ wq, const float* __restrict__ wk,
    const float* __restrict__ wv, const float* __restrict__ bq, const float* __restrict__ bk,
    const float* __restrict__ bv, __half* __restrict__ xb, __half* __restrict__ wcat,
    float* __restrict__ bcat, float* __restrict__ Zpart) {
  const int NX4 = (M_ * D_) / 4;
  const int NW4 = (D_ * D_) / 4;
  const int TOT = NX4 + 3 * NW4;
  int tid0 = blockIdx.x * 256 + threadIdx.x;
  int stride = gridDim.x * 256;
  for (int i = tid0; i < TOT; i += stride) {
    float4 f; __half* dst;
    if (i < NX4) {
      f = ((const float4*)x)[i];
      dst = xb + 4 * (size_t)i;
    } else {
      int j = i - NX4; int w = j / NW4; int o = j - w * NW4;
      const float* src = (w == 0) ? wq : (w == 1) ? wk : wv;
      f = ((const float4*)src)[o];
      dst = wcat + (size_t)w * (D_ * D_) + 4 * (size_t)o;
    }
    __half h0 = __float2half(f.x), h1 = __float2half(f.y),
           h2 = __float2half(f.z), h3 = __float2half(f.w);
    ushort4 u = { __half_as_ushort(h0), __half_as_ushort(h1),
                  __half_as_ushort(h2), __half_as_ushort(h3) };
    *((ushort4*)dst) = u;
  }
  if (tid0 < NC_)
    bcat[tid0] = (tid0 < 1024) ? bq[tid0] : (tid0 < 2048) ? bk[tid0 - 1024] : bv[tid0 - 2048];
  for (int i = tid0; i < M_ * 32; i += stride) Zpart[i] = 0.f;
}

// ---------------- K2: fused QKV GEMM (round-1 128^2, proven 59us) ---------
__global__ __launch_bounds__(256) void k_qkv(
    const __half* __restrict__ xb, const __half* __restrict__ wcat,
    const float* __restrict__ bcat,
    __half* __restrict__ q, __half* __restrict__ kx, __half* __restrict__ v) {
  __shared__ __align__(16) char smem[32768];
  char* As = smem; char* Bs = smem + 16384;
  int bid = blockIdx.x;
  int bm = bid / 24, bn = bid % 24;
  f32x4 acc[4][4];
#pragma unroll
  for (int i = 0; i < 4; ++i)
#pragma unroll
    for (int j = 0; j < 4; ++j) acc[i][j] = f32x4{0.f, 0.f, 0.f, 0.f};
  gemm128_core(xb + (size_t)bm * 128 * D_, wcat + (size_t)bn * 128 * D_, As, Bs, acc);

  const int lane = threadIdx.x & 63;
  const int wave = threadIdx.x >> 6;
  const int wm = wave >> 1, wn = wave & 1;
  int sel = bn >> 3;                       // 0=q 1=k 2=v (BN=128 divides 1024)
  __half* outp = (sel == 0) ? q : (sel == 1) ? kx : v;
#pragma unroll
  for (int nf = 0; nf < 4; ++nf) {
    int nloc = wn * 64 + nf * 16 + (lane & 15);
    float bias = bcat[bn * 128 + nloc];
    int ncol = (bn & 7) * 128 + nloc;
#pragma unroll
    for (int mf = 0; mf < 4; ++mf) {
#pragma unroll
      for (int r = 0; r < 4; ++r) {
        int m = bm * 128 + wm * 64 + mf * 16 + (lane >> 4) * 4 + r;
        outp[(size_t)m * D_ + ncol] = __float2half(acc[mf][nf][r] + bias);
      }
    }
  }
}

// ---------------- K3: upper-triangle QK^T row stats (256^2 8-phase) --------
__global__ __launch_bounds__(512, 2) void k_stats256(
    const __half* __restrict__ q, const __half* __restrict__ kx,
    float* __restrict__ Zpart, float* __restrict__ dexp) {
  __shared__ __align__(16) char smem[131072];
  int bid = blockIdx.x;
  int tile = (bid & 7) * 18 + (bid >> 3);       // 144 = 8*18
  int b = tile / 36;
  int r = tile % 36;
  int ti = 0;
  while (r >= 8 - ti) { r -= 8 - ti; ++ti; }
  int tj = ti + r;

  f32x4 acc[8][4];
#pragma unroll
  for (int i = 0; i < 8; ++i)
#pragma unroll
    for (int j = 0; j < 4; ++j) acc[i][j] = f32x4{0.f, 0.f, 0.f, 0.f};

  const size_t base = (size_t)b * N_ * D_;
  gemm256_8ph((const char*)(q + base + (size_t)ti * 256 * D_),
              (const char*)(kx + base + (size_t)tj * 256 * D_), smem, acc);

  const int lane = threadIdx.x & 63;
  const int wave = threadIdx.x >> 6;
  const int wm = wave >> 2, wn = wave & 3;
  const bool offd = (tj > ti);
  const float scale = 0.03125f;                 // 1/sqrt(1024)
  int zr0 = b * N_ + ti * 256;
#pragma unroll
  for (int mf = 0; mf < 8; ++mf) {
#pragma unroll
    for (int rr = 0; rr < 4; ++rr) {
      int il = wm * 128 + mf * 16 + (lane >> 4) * 4 + rr;
      float ssum = 0.f;
#pragma unroll
      for (int nf = 0; nf < 4; ++nf) {
        int jl = wn * 64 + nf * 16 + (lane & 15);
        float e = __expf(acc[mf][nf][rr] * scale);
        bool keep = offd || (jl >= il);
        if (!offd && jl == il) dexp[zr0 + il] = e;
        ssum += keep ? e : 0.f;
      }
      ssum += __shfl_xor(ssum, 1);
      ssum += __shfl_xor(ssum, 2);
      ssum += __shfl_xor(ssum, 4);
      ssum += __shfl_xor(ssum, 8);
      if ((lane & 15) == 0)
        Zpart[(size_t)(zr0 + il) * 32 + tj * 4 + wn] = ssum;
    }
  }
}

// ---------------- K4a: v chunk sums + per-row 1/D, dexp/D ----------------
__global__ __launch_bounds__(256) void k_mid(
    const __half* __restrict__ v, const float* __restrict__ Zpart,
    const float* __restrict__ dexp, float* __restrict__ Sv,
    float* __restrict__ invD, float* __restrict__ cdiag) {
  int tid = blockIdx.x * 256 + threadIdx.x;     // 65536 threads
  int b = tid >> 14, c = (tid >> 10) & 15, d = tid & 1023;
  const __half* vp = v + ((size_t)(b * N_ + c * 128)) * D_ + d;
  float s = 0.f;
#pragma unroll 8
  for (int r2 = 0; r2 < 128; ++r2) s += __half2float(vp[(size_t)r2 * D_]);
  Sv[tid] = s;
  if (tid < M_) {
    float z = 0.f;
#pragma unroll
    for (int t = 0; t < 32; ++t) z += Zpart[(size_t)tid * 32 + t];
    float Dd = (float)(tid & (N_ - 1)) + z;     // i + sum_{j>=i} exp(s_ij)
    float iv = 1.f / Dd;
    invD[tid] = iv;
    cdiag[tid] = dexp[tid] * iv;
  }
}

// ---------------- K4b: prefix-scan blend -> output ----------------
__global__ __launch_bounds__(256) void k_out(
    const __half* __restrict__ v, const float* __restrict__ Sv,
    const float* __restrict__ invD, const float* __restrict__ cdiag,
    float* __restrict__ out) {
  int tid = blockIdx.x * 256 + threadIdx.x;
  int b = tid >> 14, c = (tid >> 10) & 15, d = tid & 1023;
  float run = 0.f;
  for (int cc = 0; cc < c; ++cc) run += Sv[((b << 4) + cc) * 1024 + d];
  const __half* vp = v + ((size_t)(b * N_ + c * 128)) * D_ + d;
  float* op = out + ((size_t)(b * N_ + c * 128)) * D_ + d;
  int zi0 = b * N_ + c * 128;
#pragma unroll 4
  for (int r2 = 0; r2 < 128; ++r2) {
    float vi = __half2float(vp[(size_t)r2 * D_]);
    op[(size_t)r2 * D_] = run * invD[zi0 + r2] + cdiag[zi0 + r2] * vi;
    run += vi;
  }
}

extern "C" void kernel_launch(void* const* d_in, const int* in_sizes, int n_in,
                              void* d_out, int out_size, void* d_ws, size_t ws_size,
                              hipStream_t stream) {
  const float* x  = (const float*)d_in[0];
  const float* wq = (const float*)d_in[1];
  const float* bq = (const float*)d_in[2];
  const float* wk = (const float*)d_in[3];
  const float* bk = (const float*)d_in[4];
  const float* wv = (const float*)d_in[5];
  const float* bv = (const float*)d_in[6];
  float* out = (float*)d_out;
  char* ws = (char*)d_ws;

  __half* wcat = (__half*)(ws + OFF_WCAT);
  float*  bcat = (float*)(ws + OFF_BCAT);
  __half* xb   = (__half*)(ws + OFF_XB);
  __half* q    = (__half*)(ws + OFF_Q);
  __half* k    = (__half*)(ws + OFF_K);
  __half* v    = (__half*)(ws + OFF_V);
  float* Zpart = (float*)(ws + OFF_ZP);
  float* dexp  = (float*)(ws + OFF_DEXP);
  float* Sv    = (float*)(ws + OFF_SV);
  float* invD  = (float*)(ws + OFF_INVD);
  float* cdiag = (float*)(ws + OFF_CD);

  k_prep<<<dim3(2048), dim3(256), 0, stream>>>(x, wq, wk, wv, bq, bk, bv, xb, wcat, bcat, Zpart);
  k_qkv<<<dim3(64 * 24), dim3(256), 0, stream>>>(xb, wcat, bcat, q, k, v);
  k_stats256<<<dim3(144), dim3(512), 0, stream>>>(q, k, Zpart, dexp);
  k_mid<<<dim3(256), dim3(256), 0, stream>>>(v, Zpart, dexp, Sv, invD, cdiag);
  k_out<<<dim3(256), dim3(256), 0, stream>>>(v, Sv, invD, cdiag, out);
}

// Round 5
// 136.768 us; speedup vs baseline: 1.0566x; 1.0046x over previous
//
#include <hip/hip_runtime.h>
#include <hip/hip_fp16.h>
#include <cstdint>

typedef _Float16 half8_t __attribute__((ext_vector_type(8)));
typedef float f32x4 __attribute__((ext_vector_type(4)));

#define D_ 1024
#define B_ 4
#define N_ 2048
#define M_ (B_*N_)   // 8192 rows
#define NC_ 3072     // fused q|k|v output cols

// ---------------- workspace layout (bytes, all 256-aligned) ----------------
#define OFF_WCAT  0u            // 3072*1024*2  = 6291456
#define OFF_BCAT  6291456u      // 3072*4       = 12288
#define OFF_XB    6303744u      // 8192*1024*2  = 16777216
#define OFF_Q     23080960u
#define OFF_K     39858176u
#define OFF_V     56635392u
#define OFF_ZP    73412608u     // 8192*32*4    = 1048576
#define OFF_DEXP  74461184u     // 8192*4      = 32768
#define OFF_SV    74493952u     // 4*64*1024*4 = 1048576 (32-row chunks)
#define OFF_INVD  75542528u     // 8192*4
#define OFF_CD    75575296u     // 8192*4  (ends 75608064)

// ---------------- async global->LDS, 16B per lane ----------------
__device__ __forceinline__ void gload_lds16(const void* g, void* l) {
  __builtin_amdgcn_global_load_lds(
      (const __attribute__((address_space(1))) unsigned int*)(uintptr_t)g,
      (__attribute__((address_space(3))) unsigned int*)(uintptr_t)l, 16, 0, 0);
}

// ============================================================================
// 128^2 m97-structure core (round-1 proven, 59.5us for qkv)
// ============================================================================
__device__ __forceinline__ void stage128x64(const __half* rowbase, char* lds, int tid) {
#pragma unroll
  for (int inst = 0; inst < 4; ++inst) {
    int L  = inst * 4096 + tid * 16;
    int r  = L >> 7;
    int cb = L & 127;
    int cbs = cb ^ ((r & 7) << 4);
    gload_lds16((const char*)rowbase + (size_t)r * (D_ * 2) + cbs, lds + L);
  }
}

__device__ __forceinline__ half8_t ldsfrag(const char* lds, int row, int cbyte) {
  int b = (row << 7) + (cbyte ^ ((row & 7) << 4));
  return *reinterpret_cast<const half8_t*>(lds + b);
}

__device__ __forceinline__ void gemm128_core(const __half* Arow0, const __half* Brow0,
                                             char* As, char* Bs, f32x4 acc[4][4]) {
  const int tid  = threadIdx.x;
  const int lane = tid & 63;
  const int wave = tid >> 6;
  const int wm = wave >> 1, wn = wave & 1;
  for (int kt = 0; kt < 16; ++kt) {
    if (kt) __syncthreads();
    stage128x64(Arow0 + kt * 64, As, tid);
    stage128x64(Brow0 + kt * 64, Bs, tid);
    asm volatile("s_waitcnt vmcnt(0)" ::: "memory");
    __syncthreads();
#pragma unroll
    for (int kk = 0; kk < 2; ++kk) {
      const int cbyte = kk * 64 + (lane >> 4) * 16;
      half8_t a[4], b[4];
#pragma unroll
      for (int mf = 0; mf < 4; ++mf) a[mf] = ldsfrag(As, wm * 64 + mf * 16 + (lane & 15), cbyte);
#pragma unroll
      for (int nf = 0; nf < 4; ++nf) b[nf] = ldsfrag(Bs, wn * 64 + nf * 16 + (lane & 15), cbyte);
#pragma unroll
      for (int mf = 0; mf < 4; ++mf)
#pragma unroll
        for (int nf = 0; nf < 4; ++nf)
          acc[mf][nf] = __builtin_amdgcn_mfma_f32_16x16x32_f16(a[mf], b[nf], acc[mf][nf], 0, 0, 0);
    }
  }
}

// ============================================================================
// 256^2 8-phase core (round-2 proven; ~1430 TF in k_stats256)
// ============================================================================
__device__ __forceinline__ void calc_soff(int tid, int soff[4]) {
#pragma unroll
  for (int i = 0; i < 4; ++i) {
    int L = i * 8192 + tid * 16;
    int s = L >> 10;
    int w = L & 1023;
    w ^= ((w >> 9) & 1) << 5;
    int r  = (s >> 1) * 16 + (w >> 6);
    int kb = (s & 1) * 64 + (w & 63);
    soff[i] = r * 2048 + kb;
  }
}

#define MFMA_QUAD(QM, QN)                                                     \
  _Pragma("unroll")                                                           \
  for (int ks = 0; ks < 2; ++ks)                                              \
    _Pragma("unroll")                                                         \
    for (int mf = 0; mf < 4; ++mf)                                            \
      _Pragma("unroll")                                                       \
      for (int nf = 0; nf < 2; ++nf)                                          \
        acc[(QM)*4 + mf][(QN)*2 + nf] = __builtin_amdgcn_mfma_f32_16x16x32_f16( \
            a[mf][ks], b[(QN)][nf][ks], acc[(QM)*4 + mf][(QN)*2 + nf], 0, 0, 0);

__device__ __forceinline__ void gemm256_8ph(const char* Ag, const char* Bg,
                                            char* smem, f32x4 acc[8][4]) {
  const int tid  = threadIdx.x;
  const int lane = tid & 63;
  const int wave = tid >> 6;
  const int wm = wave >> 2, wn = wave & 3;

  int soff[4];
  calc_soff(tid, soff);
  const int wlane = (((lane & 15) * 64 + (lane >> 4) * 16)) ^ (((lane >> 3) & 1) << 5);

#pragma unroll
  for (int i = 0; i < 4; ++i) gload_lds16(Ag + soff[i], smem + i * 8192 + tid * 16);
#pragma unroll
  for (int i = 0; i < 4; ++i) gload_lds16(Bg + soff[i], smem + 32768 + i * 8192 + tid * 16);
  asm volatile("s_waitcnt vmcnt(0)" ::: "memory");
  __builtin_amdgcn_s_barrier();

  for (int t = 0; t < 16; ++t) {
    char* A0  = smem + ((t & 1) << 16);
    char* B0  = A0 + 32768;
    char* A1  = smem + (((t + 1) & 1) << 16);
    char* B1s = A1 + 32768;
    const half8_t* ap = (const half8_t*)(A0 + wm * 16384 + wlane);
    const half8_t* bp = (const half8_t*)(B0 + wn * 8192 + wlane);
    const char* Agn = Ag + (t + 1) * 128;
    const char* Bgn = Bg + (t + 1) * 128;
    const bool pre = (t < 15);

    half8_t a[4][2];
    half8_t b[2][2][2];

#pragma unroll
    for (int mf = 0; mf < 4; ++mf)
#pragma unroll
      for (int ks = 0; ks < 2; ++ks)
        a[mf][ks] = ap[(mf * 2 + ks) * 64];
#pragma unroll
    for (int nf = 0; nf < 2; ++nf)
#pragma unroll
      for (int ks = 0; ks < 2; ++ks)
        b[0][nf][ks] = bp[(nf * 2 + ks) * 64];
    if (pre) {
#pragma unroll
      for (int i = 0; i < 4; ++i) gload_lds16(Agn + soff[i], A1 + i * 8192 + tid * 16);
    }
    __builtin_amdgcn_s_barrier();
    asm volatile("s_waitcnt lgkmcnt(0)" ::: "memory");
    __builtin_amdgcn_s_setprio(1);
    MFMA_QUAD(0, 0)
    __builtin_amdgcn_s_setprio(0);
    __builtin_amdgcn_s_barrier();

#pragma unroll
    for (int nf = 0; nf < 2; ++nf)
#pragma unroll
      for (int ks = 0; ks < 2; ++ks)
        b[1][nf][ks] = bp[((2 + nf) * 2 + ks) * 64];
    if (pre) {
#pragma unroll
      for (int i = 0; i < 4; ++i) gload_lds16(Bgn + soff[i], B1s + i * 8192 + tid * 16);
    }
    __builtin_amdgcn_s_barrier();
    asm volatile("s_waitcnt lgkmcnt(0)" ::: "memory");
    __builtin_amdgcn_s_setprio(1);
    MFMA_QUAD(0, 1)
    __builtin_amdgcn_s_setprio(0);
    __builtin_amdgcn_s_barrier();

#pragma unroll
    for (int mf = 0; mf < 4; ++mf)
#pragma unroll
      for (int ks = 0; ks < 2; ++ks)
        a[mf][ks] = ap[((4 + mf) * 2 + ks) * 64];
    __builtin_amdgcn_s_barrier();
    asm volatile("s_waitcnt lgkmcnt(0)" ::: "memory");
    __builtin_amdgcn_s_setprio(1);
    MFMA_QUAD(1, 0)
    __builtin_amdgcn_s_setprio(0);
    __builtin_amdgcn_s_barrier();

    __builtin_amdgcn_s_setprio(1);
    MFMA_QUAD(1, 1)
    __builtin_amdgcn_s_setprio(0);
    if (pre) asm volatile("s_waitcnt vmcnt(0)" ::: "memory");
    __builtin_amdgcn_s_barrier();
  }
}

// ---------------- K1: fp32->fp16 convert + zero partials ----------------
__global__ __launch_bounds__(256) void k_prep(
    const float* __restrict__ x, const float* __restrict__ wq, const float* __restrict__ wk,
    const float* __restrict__ wv, const float* __restrict__ bq, const float* __restrict__ bk,
    const float* __restrict__ bv, __half* __restrict__ xb, __half* __restrict__ wcat,
    float* __restrict__ bcat, float* __restrict__ Zpart) {
  const int NX4 = (M_ * D_) / 4;
  const int NW4 = (D_ * D_) / 4;
  const int TOT = NX4 + 3 * NW4;
  int tid0 = blockIdx.x * 256 + threadIdx.x;
  int stride = gridDim.x * 256;
  for (int i = tid0; i < TOT; i += stride) {
    float4 f; __half* dst;
    if (i < NX4) {
      f = ((const float4*)x)[i];
      dst = xb + 4 * (size_t)i;
    } else {
      int j = i - NX4; int w = j / NW4; int o = j - w * NW4;
      const float* src = (w == 0) ? wq : (w == 1) ? wk : wv;
      f = ((const float4*)src)[o];
      dst = wcat + (size_t)w * (D_ * D_) + 4 * (size_t)o;
    }
    __half h0 = __float2half(f.x), h1 = __float2half(f.y),
           h2 = __float2half(f.z), h3 = __float2half(f.w);
    ushort4 u = { __half_as_ushort(h0), __half_as_ushort(h1),
                  __half_as_ushort(h2), __half_as_ushort(h3) };
    *((ushort4*)dst) = u;
  }
  if (tid0 < NC_)
    bcat[tid0] = (tid0 < 1024) ? bq[tid0] : (tid0 < 2048) ? bk[tid0 - 1024] : bv[tid0 - 2048];
  for (int i = tid0; i < M_ * 32; i += stride) Zpart[i] = 0.f;
}

// ---------------- K2: fused QKV GEMM (128^2, proven) ----------------------
__global__ __launch_bounds__(256) void k_qkv(
    const __half* __restrict__ xb, const __half* __restrict__ wcat,
    const float* __restrict__ bcat,
    __half* __restrict__ q, __half* __restrict__ kx, __half* __restrict__ v) {
  __shared__ __align__(16) char smem[32768];
  char* As = smem; char* Bs = smem + 16384;
  int bid = blockIdx.x;
  int bm = bid / 24, bn = bid % 24;
  f32x4 acc[4][4];
#pragma unroll
  for (int i = 0; i < 4; ++i)
#pragma unroll
    for (int j = 0; j < 4; ++j) acc[i][j] = f32x4{0.f, 0.f, 0.f, 0.f};
  gemm128_core(xb + (size_t)bm * 128 * D_, wcat + (size_t)bn * 128 * D_, As, Bs, acc);

  const int lane = threadIdx.x & 63;
  const int wave = threadIdx.x >> 6;
  const int wm = wave >> 1, wn = wave & 1;
  int sel = bn >> 3;
  __half* outp = (sel == 0) ? q : (sel == 1) ? kx : v;
#pragma unroll
  for (int nf = 0; nf < 4; ++nf) {
    int nloc = wn * 64 + nf * 16 + (lane & 15);
    float bias = bcat[bn * 128 + nloc];
    int ncol = (bn & 7) * 128 + nloc;
#pragma unroll
    for (int mf = 0; mf < 4; ++mf) {
#pragma unroll
      for (int r = 0; r < 4; ++r) {
        int m = bm * 128 + wm * 64 + mf * 16 + (lane >> 4) * 4 + r;
        outp[(size_t)m * D_ + ncol] = __float2half(acc[mf][nf][r] + bias);
      }
    }
  }
}

// ---------------- K3: upper-triangle QK^T row stats (256^2 8-phase) --------
__global__ __launch_bounds__(512, 2) void k_stats256(
    const __half* __restrict__ q, const __half* __restrict__ kx,
    float* __restrict__ Zpart, float* __restrict__ dexp) {
  __shared__ __align__(16) char smem[131072];
  int bid = blockIdx.x;
  int tile = (bid & 7) * 18 + (bid >> 3);       // 144 = 8*18
  int b = tile / 36;
  int r = tile % 36;
  int ti = 0;
  while (r >= 8 - ti) { r -= 8 - ti; ++ti; }
  int tj = ti + r;

  f32x4 acc[8][4];
#pragma unroll
  for (int i = 0; i < 8; ++i)
#pragma unroll
    for (int j = 0; j < 4; ++j) acc[i][j] = f32x4{0.f, 0.f, 0.f, 0.f};

  const size_t base = (size_t)b * N_ * D_;
  gemm256_8ph((const char*)(q + base + (size_t)ti * 256 * D_),
              (const char*)(kx + base + (size_t)tj * 256 * D_), smem, acc);

  const int lane = threadIdx.x & 63;
  const int wave = threadIdx.x >> 6;
  const int wm = wave >> 2, wn = wave & 3;
  const bool offd = (tj > ti);
  const float scale = 0.03125f;                 // 1/sqrt(1024)
  int zr0 = b * N_ + ti * 256;
#pragma unroll
  for (int mf = 0; mf < 8; ++mf) {
#pragma unroll
    for (int rr = 0; rr < 4; ++rr) {
      int il = wm * 128 + mf * 16 + (lane >> 4) * 4 + rr;
      float ssum = 0.f;
#pragma unroll
      for (int nf = 0; nf < 4; ++nf) {
        int jl = wn * 64 + nf * 16 + (lane & 15);
        float e = __expf(acc[mf][nf][rr] * scale);
        bool keep = offd || (jl >= il);
        if (!offd && jl == il) dexp[zr0 + il] = e;
        ssum += keep ? e : 0.f;
      }
      ssum += __shfl_xor(ssum, 1);
      ssum += __shfl_xor(ssum, 2);
      ssum += __shfl_xor(ssum, 4);
      ssum += __shfl_xor(ssum, 8);
      if ((lane & 15) == 0)
        Zpart[(size_t)(zr0 + il) * 32 + tj * 4 + wn] = ssum;
    }
  }
}

// ---------------- K4a: v 32-row chunk sums (vec4) + per-row 1/D -----------
// grid 256 x 256thr. block = slab (b, c∈[0,64)); thread d-group of 4 cols.
__global__ __launch_bounds__(256) void k_mid(
    const __half* __restrict__ v, const float* __restrict__ Zpart,
    const float* __restrict__ dexp, float* __restrict__ Sv,
    float* __restrict__ invD, float* __restrict__ cdiag) {
  int slab = blockIdx.x;                 // 0..255
  int b = slab >> 6, c = slab & 63;
  int dg = threadIdx.x;                  // 0..255
  int d0 = dg * 4;
  const ushort4* vp = (const ushort4*)(v + ((size_t)(b * N_ + c * 32)) * D_ + d0);
  f32x4 s = {0.f, 0.f, 0.f, 0.f};
#pragma unroll 8
  for (int r2 = 0; r2 < 32; ++r2) {
    ushort4 u = vp[r2 * (D_ / 4)];
    s[0] += __half2float(__ushort_as_half(u.x));
    s[1] += __half2float(__ushort_as_half(u.y));
    s[2] += __half2float(__ushort_as_half(u.z));
    s[3] += __half2float(__ushort_as_half(u.w));
  }
  *(f32x4*)(Sv + (size_t)slab * D_ + d0) = s;

  // per-row denominators: rows handled by first 32 blocks (8192 = 32*256)
  int tid = blockIdx.x * 256 + threadIdx.x;
  if (tid < M_) {
    const f32x4* zp = (const f32x4*)(Zpart + (size_t)tid * 32);
    f32x4 z4 = {0.f, 0.f, 0.f, 0.f};
#pragma unroll
    for (int t = 0; t < 8; ++t) {
      f32x4 zz = zp[t];
      z4[0] += zz[0]; z4[1] += zz[1]; z4[2] += zz[2]; z4[3] += zz[3];
    }
    float z = z4[0] + z4[1] + z4[2] + z4[3];
    float Dd = (float)(tid & (N_ - 1)) + z;
    float iv = 1.f / Dd;
    invD[tid] = iv;
    cdiag[tid] = dexp[tid] * iv;
  }
}

// ---------------- K4b: prefix-scan blend -> output (vec4) -----------------
__global__ __launch_bounds__(256) void k_out(
    const __half* __restrict__ v, const float* __restrict__ Sv,
    const float* __restrict__ invD, const float* __restrict__ cdiag,
    float* __restrict__ out) {
  __shared__ float sInv[32], sCd[32];
  int slab = blockIdx.x;
  int b = slab >> 6, c = slab & 63;
  int dg = threadIdx.x;
  int d0 = dg * 4;
  int zi0 = b * N_ + c * 32;
  if (dg < 32) sInv[dg] = invD[zi0 + dg];
  else if (dg < 64) sCd[dg - 32] = cdiag[zi0 + dg - 32];
  __syncthreads();

  f32x4 run = {0.f, 0.f, 0.f, 0.f};
  for (int cc = 0; cc < c; ++cc) {
    f32x4 sv = *(const f32x4*)(Sv + (size_t)((b << 6) + cc) * D_ + d0);
    run[0] += sv[0]; run[1] += sv[1]; run[2] += sv[2]; run[3] += sv[3];
  }
  const ushort4* vp = (const ushort4*)(v + (size_t)zi0 * D_ + d0);
  float* op = out + (size_t)zi0 * D_ + d0;
#pragma unroll 4
  for (int r2 = 0; r2 < 32; ++r2) {
    ushort4 u = vp[r2 * (D_ / 4)];
    f32x4 vi;
    vi[0] = __half2float(__ushort_as_half(u.x));
    vi[1] = __half2float(__ushort_as_half(u.y));
    vi[2] = __half2float(__ushort_as_half(u.z));
    vi[3] = __half2float(__ushort_as_half(u.w));
    float iv = sInv[r2], cd = sCd[r2];
    f32x4 o;
    o[0] = run[0] * iv + cd * vi[0];
    o[1] = run[1] * iv + cd * vi[1];
    o[2] = run[2] * iv + cd * vi[2];
    o[3] = run[3] * iv + cd * vi[3];
    *(f32x4*)(op + (size_t)r2 * D_) = o;
    run[0] += vi[0]; run[1] += vi[1]; run[2] += vi[2]; run[3] += vi[3];
  }
}

extern "C" void kernel_launch(void* const* d_in, const int* in_sizes, int n_in,
                              void* d_out, int out_size, void* d_ws, size_t ws_size,
                              hipStream_t stream) {
  const float* x  = (const float*)d_in[0];
  const float* wq = (const float*)d_in[1];
  const float* bq = (const float*)d_in[2];
  const float* wk = (const float*)d_in[3];
  const float* bk = (const float*)d_in[4];
  const float* wv = (const float*)d_in[5];
  const float* bv = (const float*)d_in[6];
  float* out = (float*)d_out;
  char* ws = (char*)d_ws;

  __half* wcat = (__half*)(ws + OFF_WCAT);
  float*  bcat = (float*)(ws + OFF_BCAT);
  __half* xb   = (__half*)(ws + OFF_XB);
  __half* q    = (__half*)(ws + OFF_Q);
  __half* k    = (__half*)(ws + OFF_K);
  __half* v    = (__half*)(ws + OFF_V);
  float* Zpart = (float*)(ws + OFF_ZP);
  float* dexp  = (float*)(ws + OFF_DEXP);
  float* Sv    = (float*)(ws + OFF_SV);
  float* invD  = (float*)(ws + OFF_INVD);
  float* cdiag = (float*)(ws + OFF_CD);

  k_prep<<<dim3(2048), dim3(256), 0, stream>>>(x, wq, wk, wv, bq, bk, bv, xb, wcat, bcat, Zpart);
  k_qkv<<<dim3(64 * 24), dim3(256), 0, stream>>>(xb, wcat, bcat, q, k, v);
  k_stats256<<<dim3(144), dim3(512), 0, stream>>>(q, k, Zpart, dexp);
  k_mid<<<dim3(256), dim3(256), 0, stream>>>(v, Zpart, dexp, Sv, invD, cdiag);
  k_out<<<dim3(256), dim3(256), 0, stream>>>(v, Sv, invD, cdiag, out);
}

// Round 6
// 133.689 us; speedup vs baseline: 1.0810x; 1.0230x over previous
//
#include <hip/hip_runtime.h>
#include <hip/hip_fp16.h>
#include <cstdint>

typedef _Float16 half8_t __attribute__((ext_vector_type(8)));
typedef float f32x4 __attribute__((ext_vector_type(4)));

#define D_ 1024
#define B_ 4
#define N_ 2048
#define M_ (B_*N_)   // 8192 rows
#define NC_ 3072     // fused q|k|v output cols

// ---------------- workspace layout (bytes, all 256-aligned) ----------------
#define OFF_WCAT  0u            // 3072*1024*2  = 6291456
#define OFF_BCAT  6291456u      // 3072*4       = 12288
#define OFF_XB    6303744u      // 8192*1024*2  = 16777216
#define OFF_Q     23080960u
#define OFF_K     39858176u
#define OFF_V     56635392u
#define OFF_ZP    73412608u     // 8192*32*4    = 1048576
#define OFF_DEXP  74461184u     // 8192*4      = 32768
#define OFF_SV    74493952u     // 4*64*1024*4 = 1048576 (32-row chunks, f32)

// ---------------- async global->LDS, 16B per lane ----------------
__device__ __forceinline__ void gload_lds16(const void* g, void* l) {
  __builtin_amdgcn_global_load_lds(
      (const __attribute__((address_space(1))) unsigned int*)(uintptr_t)g,
      (__attribute__((address_space(3))) unsigned int*)(uintptr_t)l, 16, 0, 0);
}

// ============================================================================
// 128^2 m97-structure core (proven 59.5us for qkv)
// ============================================================================
__device__ __forceinline__ void stage128x64(const __half* rowbase, char* lds, int tid) {
#pragma unroll
  for (int inst = 0; inst < 4; ++inst) {
    int L  = inst * 4096 + tid * 16;
    int r  = L >> 7;
    int cb = L & 127;
    int cbs = cb ^ ((r & 7) << 4);
    gload_lds16((const char*)rowbase + (size_t)r * (D_ * 2) + cbs, lds + L);
  }
}

__device__ __forceinline__ half8_t ldsfrag(const char* lds, int row, int cbyte) {
  int b = (row << 7) + (cbyte ^ ((row & 7) << 4));
  return *reinterpret_cast<const half8_t*>(lds + b);
}

__device__ __forceinline__ void gemm128_core(const __half* Arow0, const __half* Brow0,
                                             char* As, char* Bs, f32x4 acc[4][4]) {
  const int tid  = threadIdx.x;
  const int lane = tid & 63;
  const int wave = tid >> 6;
  const int wm = wave >> 1, wn = wave & 1;
  for (int kt = 0; kt < 16; ++kt) {
    if (kt) __syncthreads();
    stage128x64(Arow0 + kt * 64, As, tid);
    stage128x64(Brow0 + kt * 64, Bs, tid);
    asm volatile("s_waitcnt vmcnt(0)" ::: "memory");
    __syncthreads();
#pragma unroll
    for (int kk = 0; kk < 2; ++kk) {
      const int cbyte = kk * 64 + (lane >> 4) * 16;
      half8_t a[4], b[4];
#pragma unroll
      for (int mf = 0; mf < 4; ++mf) a[mf] = ldsfrag(As, wm * 64 + mf * 16 + (lane & 15), cbyte);
#pragma unroll
      for (int nf = 0; nf < 4; ++nf) b[nf] = ldsfrag(Bs, wn * 64 + nf * 16 + (lane & 15), cbyte);
#pragma unroll
      for (int mf = 0; mf < 4; ++mf)
#pragma unroll
        for (int nf = 0; nf < 4; ++nf)
          acc[mf][nf] = __builtin_amdgcn_mfma_f32_16x16x32_f16(a[mf], b[nf], acc[mf][nf], 0, 0, 0);
    }
  }
}

// ============================================================================
// 256^2 8-phase core (round-2 proven for k_stats256)
// ============================================================================
__device__ __forceinline__ void calc_soff(int tid, int soff[4]) {
#pragma unroll
  for (int i = 0; i < 4; ++i) {
    int L = i * 8192 + tid * 16;
    int s = L >> 10;
    int w = L & 1023;
    w ^= ((w >> 9) & 1) << 5;
    int r  = (s >> 1) * 16 + (w >> 6);
    int kb = (s & 1) * 64 + (w & 63);
    soff[i] = r * 2048 + kb;
  }
}

#define MFMA_QUAD(QM, QN)                                                     \
  _Pragma("unroll")                                                           \
  for (int ks = 0; ks < 2; ++ks)                                              \
    _Pragma("unroll")                                                         \
    for (int mf = 0; mf < 4; ++mf)                                            \
      _Pragma("unroll")                                                       \
      for (int nf = 0; nf < 2; ++nf)                                          \
        acc[(QM)*4 + mf][(QN)*2 + nf] = __builtin_amdgcn_mfma_f32_16x16x32_f16( \
            a[mf][ks], b[(QN)][nf][ks], acc[(QM)*4 + mf][(QN)*2 + nf], 0, 0, 0);

__device__ __forceinline__ void gemm256_8ph(const char* Ag, const char* Bg,
                                            char* smem, f32x4 acc[8][4]) {
  const int tid  = threadIdx.x;
  const int lane = tid & 63;
  const int wave = tid >> 6;
  const int wm = wave >> 2, wn = wave & 3;

  int soff[4];
  calc_soff(tid, soff);
  const int wlane = (((lane & 15) * 64 + (lane >> 4) * 16)) ^ (((lane >> 3) & 1) << 5);

#pragma unroll
  for (int i = 0; i < 4; ++i) gload_lds16(Ag + soff[i], smem + i * 8192 + tid * 16);
#pragma unroll
  for (int i = 0; i < 4; ++i) gload_lds16(Bg + soff[i], smem + 32768 + i * 8192 + tid * 16);
  asm volatile("s_waitcnt vmcnt(0)" ::: "memory");
  __builtin_amdgcn_s_barrier();

  for (int t = 0; t < 16; ++t) {
    char* A0  = smem + ((t & 1) << 16);
    char* B0  = A0 + 32768;
    char* A1  = smem + (((t + 1) & 1) << 16);
    char* B1s = A1 + 32768;
    const half8_t* ap = (const half8_t*)(A0 + wm * 16384 + wlane);
    const half8_t* bp = (const half8_t*)(B0 + wn * 8192 + wlane);
    const char* Agn = Ag + (t + 1) * 128;
    const char* Bgn = Bg + (t + 1) * 128;
    const bool pre = (t < 15);

    half8_t a[4][2];
    half8_t b[2][2][2];

#pragma unroll
    for (int mf = 0; mf < 4; ++mf)
#pragma unroll
      for (int ks = 0; ks < 2; ++ks)
        a[mf][ks] = ap[(mf * 2 + ks) * 64];
#pragma unroll
    for (int nf = 0; nf < 2; ++nf)
#pragma unroll
      for (int ks = 0; ks < 2; ++ks)
        b[0][nf][ks] = bp[(nf * 2 + ks) * 64];
    if (pre) {
#pragma unroll
      for (int i = 0; i < 4; ++i) gload_lds16(Agn + soff[i], A1 + i * 8192 + tid * 16);
    }
    __builtin_amdgcn_s_barrier();
    asm volatile("s_waitcnt lgkmcnt(0)" ::: "memory");
    __builtin_amdgcn_s_setprio(1);
    MFMA_QUAD(0, 0)
    __builtin_amdgcn_s_setprio(0);
    __builtin_amdgcn_s_barrier();

#pragma unroll
    for (int nf = 0; nf < 2; ++nf)
#pragma unroll
      for (int ks = 0; ks < 2; ++ks)
        b[1][nf][ks] = bp[((2 + nf) * 2 + ks) * 64];
    if (pre) {
#pragma unroll
      for (int i = 0; i < 4; ++i) gload_lds16(Bgn + soff[i], B1s + i * 8192 + tid * 16);
    }
    __builtin_amdgcn_s_barrier();
    asm volatile("s_waitcnt lgkmcnt(0)" ::: "memory");
    __builtin_amdgcn_s_setprio(1);
    MFMA_QUAD(0, 1)
    __builtin_amdgcn_s_setprio(0);
    __builtin_amdgcn_s_barrier();

#pragma unroll
    for (int mf = 0; mf < 4; ++mf)
#pragma unroll
      for (int ks = 0; ks < 2; ++ks)
        a[mf][ks] = ap[((4 + mf) * 2 + ks) * 64];
    __builtin_amdgcn_s_barrier();
    asm volatile("s_waitcnt lgkmcnt(0)" ::: "memory");
    __builtin_amdgcn_s_setprio(1);
    MFMA_QUAD(1, 0)
    __builtin_amdgcn_s_setprio(0);
    __builtin_amdgcn_s_barrier();

    __builtin_amdgcn_s_setprio(1);
    MFMA_QUAD(1, 1)
    __builtin_amdgcn_s_setprio(0);
    if (pre) asm volatile("s_waitcnt vmcnt(0)" ::: "memory");
    __builtin_amdgcn_s_barrier();
  }
}

// ---------------- K1: fp32->fp16 convert (no Zpart zeroing needed) --------
__global__ __launch_bounds__(256) void k_prep(
    const float* __restrict__ x, const float* __restrict__ wq, const float* __restrict__ wk,
    const float* __restrict__ wv, const float* __restrict__ bq, const float* __restrict__ bk,
    const float* __restrict__ bv, __half* __restrict__ xb, __half* __restrict__ wcat,
    float* __restrict__ bcat) {
  const int NX4 = (M_ * D_) / 4;
  const int NW4 = (D_ * D_) / 4;
  const int TOT = NX4 + 3 * NW4;
  int tid0 = blockIdx.x * 256 + threadIdx.x;
  int stride = gridDim.x * 256;
  for (int i = tid0; i < TOT; i += stride) {
    float4 f; __half* dst;
    if (i < NX4) {
      f = ((const float4*)x)[i];
      dst = xb + 4 * (size_t)i;
    } else {
      int j = i - NX4; int w = j / NW4; int o = j - w * NW4;
      const float* src = (w == 0) ? wq : (w == 1) ? wk : wv;
      f = ((const float4*)src)[o];
      dst = wcat + (size_t)w * (D_ * D_) + 4 * (size_t)o;
    }
    __half h0 = __float2half(f.x), h1 = __float2half(f.y),
           h2 = __float2half(f.z), h3 = __float2half(f.w);
    ushort4 u = { __half_as_ushort(h0), __half_as_ushort(h1),
                  __half_as_ushort(h2), __half_as_ushort(h3) };
    *((ushort4*)dst) = u;
  }
  if (tid0 < NC_)
    bcat[tid0] = (tid0 < 1024) ? bq[tid0] : (tid0 < 2048) ? bk[tid0 - 1024] : bv[tid0 - 2048];
}

// ---------------- K2: fused QKV GEMM (128^2) + v chunk-sum epilogue -------
__global__ __launch_bounds__(256) void k_qkv(
    const __half* __restrict__ xb, const __half* __restrict__ wcat,
    const float* __restrict__ bcat,
    __half* __restrict__ q, __half* __restrict__ kx, __half* __restrict__ v,
    float* __restrict__ Sv) {
  __shared__ __align__(16) char smem[32768];
  char* As = smem; char* Bs = smem + 16384;
  int bid = blockIdx.x;
  int bm = bid / 24, bn = bid % 24;
  f32x4 acc[4][4];
#pragma unroll
  for (int i = 0; i < 4; ++i)
#pragma unroll
    for (int j = 0; j < 4; ++j) acc[i][j] = f32x4{0.f, 0.f, 0.f, 0.f};
  gemm128_core(xb + (size_t)bm * 128 * D_, wcat + (size_t)bn * 128 * D_, As, Bs, acc);

  const int lane = threadIdx.x & 63;
  const int wave = threadIdx.x >> 6;
  const int wm = wave >> 1, wn = wave & 1;
  int sel = bn >> 3;
  __half* outp = (sel == 0) ? q : (sel == 1) ? kx : v;
#pragma unroll
  for (int nf = 0; nf < 4; ++nf) {
    int nloc = wn * 64 + nf * 16 + (lane & 15);
    float bias = bcat[bn * 128 + nloc];
    int ncol = (bn & 7) * 128 + nloc;
#pragma unroll
    for (int mf = 0; mf < 4; ++mf) {
#pragma unroll
      for (int r = 0; r < 4; ++r) {
        int m = bm * 128 + wm * 64 + mf * 16 + (lane >> 4) * 4 + r;
        outp[(size_t)m * D_ + ncol] = __float2half(acc[mf][nf][r] + bias);
      }
    }
    // v-blocks: accumulate 32-row chunk column-sums straight from registers
    if (sel == 2) {
      int bloc  = bm >> 4;            // batch
      int cbase = (bm & 15) * 4;      // first 32-row chunk of this 128-row panel
#pragma unroll
      for (int chl = 0; chl < 2; ++chl) {
        float s = 8.f * bias;         // 8 rows per lane in this chunk
#pragma unroll
        for (int mf2 = 0; mf2 < 2; ++mf2)
#pragma unroll
          for (int r = 0; r < 4; ++r)
            s += acc[chl * 2 + mf2][nf][r];
        s += __shfl_xor(s, 16);
        s += __shfl_xor(s, 32);
        if ((lane >> 4) == 0) {
          int ch = wm * 2 + chl;      // chunk within panel (rows wm*64+chl*32..+32)
          Sv[(size_t)((bloc << 6) + cbase + ch) * D_ + ncol] = s;
        }
      }
    }
  }
}

// ---------------- K3: upper-triangle QK^T row stats (256^2 8-phase) --------
__global__ __launch_bounds__(512, 2) void k_stats256(
    const __half* __restrict__ q, const __half* __restrict__ kx,
    float* __restrict__ Zpart, float* __restrict__ dexp) {
  __shared__ __align__(16) char smem[131072];
  int bid = blockIdx.x;
  int tile = (bid & 7) * 18 + (bid >> 3);       // 144 = 8*18
  int b = tile / 36;
  int r = tile % 36;
  int ti = 0;
  while (r >= 8 - ti) { r -= 8 - ti; ++ti; }
  int tj = ti + r;

  f32x4 acc[8][4];
#pragma unroll
  for (int i = 0; i < 8; ++i)
#pragma unroll
    for (int j = 0; j < 4; ++j) acc[i][j] = f32x4{0.f, 0.f, 0.f, 0.f};

  const size_t base = (size_t)b * N_ * D_;
  gemm256_8ph((const char*)(q + base + (size_t)ti * 256 * D_),
              (const char*)(kx + base + (size_t)tj * 256 * D_), smem, acc);

  const int lane = threadIdx.x & 63;
  const int wave = threadIdx.x >> 6;
  const int wm = wave >> 2, wn = wave & 3;
  const bool offd = (tj > ti);
  const float scale = 0.03125f;                 // 1/sqrt(1024)
  int zr0 = b * N_ + ti * 256;
#pragma unroll
  for (int mf = 0; mf < 8; ++mf) {
#pragma unroll
    for (int rr = 0; rr < 4; ++rr) {
      int il = wm * 128 + mf * 16 + (lane >> 4) * 4 + rr;
      float ssum = 0.f;
#pragma unroll
      for (int nf = 0; nf < 4; ++nf) {
        int jl = wn * 64 + nf * 16 + (lane & 15);
        float e = __expf(acc[mf][nf][rr] * scale);
        bool keep = offd || (jl >= il);
        if (!offd && jl == il) dexp[zr0 + il] = e;
        ssum += keep ? e : 0.f;
      }
      ssum += __shfl_xor(ssum, 1);
      ssum += __shfl_xor(ssum, 2);
      ssum += __shfl_xor(ssum, 4);
      ssum += __shfl_xor(ssum, 8);
      if ((lane & 15) == 0)
        Zpart[(size_t)(zr0 + il) * 32 + tj * 4 + wn] = ssum;
    }
  }
}

// ---------------- K4: denom + prefix-scan blend -> output (vec4) ----------
// grid 256 blocks x 256 thr. block = slab (b, c in [0,64)) of 32 rows.
__global__ __launch_bounds__(256) void k_out(
    const __half* __restrict__ v, const float* __restrict__ Sv,
    const float* __restrict__ Zpart, const float* __restrict__ dexp,
    float* __restrict__ out) {
  __shared__ float sInv[32], sCd[32];
  int slab = blockIdx.x;
  int b = slab >> 6, c = slab & 63;
  int dg = threadIdx.x;
  int d0 = dg * 4;
  int zi0 = b * N_ + c * 32;

  // threads 0-31: per-row denominator from Zpart valid slots + dexp
  if (dg < 32) {
    int i  = c * 32 + dg;                 // row within batch
    int row = zi0 + dg;
    int t0 = (i >> 8) * 4;                // first valid slot (tile-row ti)
    float z = 0.f;
    for (int t = t0; t < 32; ++t) z += Zpart[(size_t)row * 32 + t];
    float iv = 1.f / ((float)i + z);
    sInv[dg] = iv;
    sCd[dg]  = dexp[row] * iv;
  }
  __syncthreads();

  f32x4 run = {0.f, 0.f, 0.f, 0.f};
  for (int cc = 0; cc < c; ++cc) {
    f32x4 sv = *(const f32x4*)(Sv + (size_t)((b << 6) + cc) * D_ + d0);
    run[0] += sv[0]; run[1] += sv[1]; run[2] += sv[2]; run[3] += sv[3];
  }
  const ushort4* vp = (const ushort4*)(v + (size_t)zi0 * D_ + d0);
  float* op = out + (size_t)zi0 * D_ + d0;
#pragma unroll 4
  for (int r2 = 0; r2 < 32; ++r2) {
    ushort4 u = vp[r2 * (D_ / 4)];
    f32x4 vi;
    vi[0] = __half2float(__ushort_as_half(u.x));
    vi[1] = __half2float(__ushort_as_half(u.y));
    vi[2] = __half2float(__ushort_as_half(u.z));
    vi[3] = __half2float(__ushort_as_half(u.w));
    float iv = sInv[r2], cd = sCd[r2];
    f32x4 o;
    o[0] = run[0] * iv + cd * vi[0];
    o[1] = run[1] * iv + cd * vi[1];
    o[2] = run[2] * iv + cd * vi[2];
    o[3] = run[3] * iv + cd * vi[3];
    *(f32x4*)(op + (size_t)r2 * D_) = o;
    run[0] += vi[0]; run[1] += vi[1]; run[2] += vi[2]; run[3] += vi[3];
  }
}

extern "C" void kernel_launch(void* const* d_in, const int* in_sizes, int n_in,
                              void* d_out, int out_size, void* d_ws, size_t ws_size,
                              hipStream_t stream) {
  const float* x  = (const float*)d_in[0];
  const float* wq = (const float*)d_in[1];
  const float* bq = (const float*)d_in[2];
  const float* wk = (const float*)d_in[3];
  const float* bk = (const float*)d_in[4];
  const float* wv = (const float*)d_in[5];
  const float* bv = (const float*)d_in[6];
  float* out = (float*)d_out;
  char* ws = (char*)d_ws;

  __half* wcat = (__half*)(ws + OFF_WCAT);
  float*  bcat = (float*)(ws + OFF_BCAT);
  __half* xb   = (__half*)(ws + OFF_XB);
  __half* q    = (__half*)(ws + OFF_Q);
  __half* k    = (__half*)(ws + OFF_K);
  __half* v    = (__half*)(ws + OFF_V);
  float* Zpart = (float*)(ws + OFF_ZP);
  float* dexp  = (float*)(ws + OFF_DEXP);
  float* Sv    = (float*)(ws + OFF_SV);

  k_prep<<<dim3(2048), dim3(256), 0, stream>>>(x, wq, wk, wv, bq, bk, bv, xb, wcat, bcat);
  k_qkv<<<dim3(64 * 24), dim3(256), 0, stream>>>(xb, wcat, bcat, q, k, v, Sv);
  k_stats256<<<dim3(144), dim3(512), 0, stream>>>(q, k, Zpart, dexp);
  k_out<<<dim3(256), dim3(256), 0, stream>>>(v, Sv, Zpart, dexp, out);
}